// Round 1
// baseline (29594.452 us; speedup 1.0000x reference)
//
#include <hip/hip_runtime.h>
#include <math.h>

#define SS 512
#define BB 32
#define HH 256
#define G4 1024
#define TT 11
#define NEGV (-1000.0f)

// ---------------- workspace layout (bytes) ----------------
static const size_t OFF_XE    = 0;                          // 16,777,216  : xe [B*S][256]
static const size_t OFF_XS    = 16777216ull;                // 134,217,728 : xs [2][S][B][1024]
static const size_t OFF_H0    = OFF_XS + 134217728ull;      // 33,554,432  : h0 [B*S][512]
static const size_t OFF_H1    = OFF_H0 + 33554432ull;       // 33,554,432  : h1 [B*S][512]
static const size_t OFF_FEATS = OFF_H1 + 33554432ull;       // 720,896     : feats [B][S][11]
static const size_t OFF_HBUF  = OFF_FEATS + 720896ull;      // 131,072     : h ping-pong [2 dir][2][B*256]
static const size_t OFF_CTR   = OFF_HBUF + 131072ull;       // 4,096       : barrier ctr [2][S]
// total ~209 MB

// ---------------- embedding gather ----------------
__global__ void emb_kernel(const int* __restrict__ x, const float4* __restrict__ emb,
                           float4* __restrict__ xe) {
  int idx = blockIdx.x * 256 + threadIdx.x;    // over B*S*H/4 = 1,048,576
  int bs  = idx >> 6;
  int kq  = idx & 63;
  int row = x[bs];
  xe[idx] = emb[(size_t)row * 64 + kq];
}

// ---------------- input projection GEMM ----------------
// C[m][n] = sum_k A[m][k]*W[n][k] + bias[n]  -> xs[dir][s][b][n], m = b*S+s
// 128x128 tile, 256 threads, 8x8 micro-tile, BK=8
template<int K>
__global__ __launch_bounds__(256, 2)
void proj_kernel(const float* __restrict__ A,
                 const float* __restrict__ Wf, const float* __restrict__ Wb,
                 const float* __restrict__ bf, const float* __restrict__ bb,
                 float* __restrict__ xs) {
  __shared__ float As[8][132];
  __shared__ float Bs[8][132];
  int tid = threadIdx.x;
  int dir = blockIdx.z;
  const float* W    = dir ? Wb : Wf;
  const float* bias = dir ? bb : bf;
  float* out = xs + (size_t)dir * (SS * BB * G4);
  int bm = blockIdx.x * 128;
  int bn = blockIdx.y * 128;
  int ty = tid >> 4;
  int tx = tid & 15;
  int lr = tid >> 1;
  int lk = (tid & 1) * 4;
  const float* Ap = A + (size_t)(bm + lr) * K + lk;
  const float* Wp = W + (size_t)(bn + lr) * K + lk;
  float acc[8][8];
  #pragma unroll
  for (int i = 0; i < 8; i++)
    #pragma unroll
    for (int j = 0; j < 8; j++) acc[i][j] = 0.f;

  for (int kt = 0; kt < K; kt += 8) {
    float4 av = *(const float4*)(Ap + kt);
    float4 bv = *(const float4*)(Wp + kt);
    __syncthreads();
    As[lk + 0][lr] = av.x; As[lk + 1][lr] = av.y; As[lk + 2][lr] = av.z; As[lk + 3][lr] = av.w;
    Bs[lk + 0][lr] = bv.x; Bs[lk + 1][lr] = bv.y; Bs[lk + 2][lr] = bv.z; Bs[lk + 3][lr] = bv.w;
    __syncthreads();
    #pragma unroll
    for (int k = 0; k < 8; k++) {
      float4 a0 = *(const float4*)&As[k][ty * 8];
      float4 a1 = *(const float4*)&As[k][ty * 8 + 4];
      float4 b0 = *(const float4*)&Bs[k][tx * 8];
      float4 b1 = *(const float4*)&Bs[k][tx * 8 + 4];
      float a[8] = {a0.x, a0.y, a0.z, a0.w, a1.x, a1.y, a1.z, a1.w};
      float b[8] = {b0.x, b0.y, b0.z, b0.w, b1.x, b1.y, b1.z, b1.w};
      #pragma unroll
      for (int i = 0; i < 8; i++)
        #pragma unroll
        for (int j = 0; j < 8; j++)
          acc[i][j] += a[i] * b[j];
    }
  }
  int nb = bn + tx * 8;
  float4 bias0 = *(const float4*)(bias + nb);
  float4 bias1 = *(const float4*)(bias + nb + 4);
  #pragma unroll
  for (int i = 0; i < 8; i++) {
    int gm = bm + ty * 8 + i;
    int b_ = gm >> 9;
    int s_ = gm & 511;
    float* op = out + (size_t)(s_ * BB + b_) * G4 + nb;
    float4 v0, v1;
    v0.x = acc[i][0] + bias0.x; v0.y = acc[i][1] + bias0.y;
    v0.z = acc[i][2] + bias0.z; v0.w = acc[i][3] + bias0.w;
    v1.x = acc[i][4] + bias1.x; v1.y = acc[i][5] + bias1.y;
    v1.z = acc[i][6] + bias1.z; v1.w = acc[i][7] + bias1.w;
    *(float4*)op = v0;
    *(float4*)(op + 4) = v1;
  }
}

// ---------------- recurrent scan (one bidirectional LSTM layer) ----------------
// grid (64, 2): blockIdx.x = cell-group (4 cells), blockIdx.y = direction.
// Each block: 16 gate rows {g*256 + cb*4 + c}, all 32 batches.
// Wave w (of 4) owns k-slice [w*64, w*64+64); weights live in VGPRs (loaded once).
// One agent-scope barrier per step among the 64 blocks of this direction.
__global__ __launch_bounds__(256, 1)
void scan_kernel(const float* __restrict__ xs,      // [2][S][B][1024]
                 const float* __restrict__ whhf, const float* __restrict__ whhb,
                 float* __restrict__ hbuf,          // [2][2][B*256]
                 int* __restrict__ ctr,             // [2][S]
                 float* __restrict__ hout)          // [B*S][512]
{
  int tid = threadIdx.x;
  int cb  = blockIdx.x;           // 0..63
  int dir = blockIdx.y;
  const float* whh = dir ? whhb : whhf;
  const float* xsd = xs + (size_t)dir * (SS * BB * G4);
  float* hb   = hbuf + (size_t)dir * (2 * BB * HH);
  int* myctr  = ctr + dir * SS;

  __shared__ float4 h_sh4[32 * 65];      // h[b][k] padded, float4 granularity
  __shared__ float  part[4 * 16 * 33];   // partial[w][row_local][b]

  int w    = tid >> 6;           // wave index = k-slice
  int lane = tid & 63;
  int r8   = lane >> 3;          // row pair: rows r8*2, r8*2+1
  int b8   = lane & 7;           // batches b8 + 8*jb

  // preload weights into registers: wreg[i][j] = whh[grow(r8*2+i)][w*64 + j*4 ..+3]
  float4 wreg[2][16];
  #pragma unroll
  for (int i = 0; i < 2; i++) {
    int rl   = r8 * 2 + i;
    int grow = (rl >> 2) * 256 + cb * 4 + (rl & 3);
    const float* wp = whh + (size_t)grow * 256 + w * 64;
    #pragma unroll
    for (int j = 0; j < 16; j++) wreg[i][j] = *(const float4*)(wp + j * 4);
  }

  int uc = tid >> 5;    // cell 0..3 (valid for tid<128)
  int ub = tid & 31;    // batch
  float c_state = 0.f;

  for (int s = 0; s < SS; ++s) {
    int tpos = dir ? (SS - 1 - s) : s;

    // prefetch xs gate biases for the update phase
    float xsg[4] = {0.f, 0.f, 0.f, 0.f};
    if (tid < 128) {
      const float* xp = xsd + ((size_t)(tpos * BB + ub) * G4) + cb * 4 + uc;
      #pragma unroll
      for (int g = 0; g < 4; g++) xsg[g] = xp[g * 256];
    }

    // stage h(prev) into LDS
    const float4* hsrc = (const float4*)(hb + (size_t)(s & 1) * (BB * HH));
    #pragma unroll
    for (int i = 0; i < 8; i++) {
      int idx4 = i * 256 + tid;
      int b_ = idx4 >> 6, k4 = idx4 & 63;
      h_sh4[b_ * 65 + k4] = hsrc[idx4];
    }
    __syncthreads();

    // partial dot products over this wave's k-slice
    float acc[2][4] = {{0.f,0.f,0.f,0.f},{0.f,0.f,0.f,0.f}};
    #pragma unroll
    for (int j = 0; j < 16; j++) {
      int k4 = w * 16 + j;
      float4 h0 = h_sh4[(b8 +  0) * 65 + k4];
      float4 h1 = h_sh4[(b8 +  8) * 65 + k4];
      float4 h2 = h_sh4[(b8 + 16) * 65 + k4];
      float4 h3 = h_sh4[(b8 + 24) * 65 + k4];
      #pragma unroll
      for (int i = 0; i < 2; i++) {
        float4 wv = wreg[i][j];
        acc[i][0] += wv.x * h0.x + wv.y * h0.y + wv.z * h0.z + wv.w * h0.w;
        acc[i][1] += wv.x * h1.x + wv.y * h1.y + wv.z * h1.z + wv.w * h1.w;
        acc[i][2] += wv.x * h2.x + wv.y * h2.y + wv.z * h2.z + wv.w * h2.w;
        acc[i][3] += wv.x * h3.x + wv.y * h3.y + wv.z * h3.z + wv.w * h3.w;
      }
    }
    #pragma unroll
    for (int i = 0; i < 2; i++) {
      int rl = r8 * 2 + i;
      #pragma unroll
      for (int jb = 0; jb < 4; jb++)
        part[(w * 16 + rl) * 33 + (b8 + 8 * jb)] = acc[i][jb];
    }
    __syncthreads();

    // reduce + LSTM cell update (threads 0..127: 4 cells x 32 batches)
    if (tid < 128) {
      float gv[4];
      #pragma unroll
      for (int g = 0; g < 4; g++) {
        int rl = g * 4 + uc;
        float sum = xsg[g];
        #pragma unroll
        for (int ww = 0; ww < 4; ww++) sum += part[(ww * 16 + rl) * 33 + ub];
        gv[g] = sum;
      }
      float ig = 1.f / (1.f + expf(-gv[0]));
      float fg = 1.f / (1.f + expf(-gv[1]));
      float gg = tanhf(gv[2]);
      float og = 1.f / (1.f + expf(-gv[3]));
      c_state = fg * c_state + ig * gg;
      float hv = og * tanhf(c_state);
      int col = cb * 4 + uc;
      hb[(size_t)((s + 1) & 1) * (BB * HH) + ub * HH + col] = hv;
      hout[((size_t)(ub * SS + tpos)) * 512 + dir * 256 + col] = hv;
    }

    // inter-block barrier for this direction
    __threadfence();
    __syncthreads();
    if (tid == 0) {
      __hip_atomic_fetch_add(&myctr[s], 1, __ATOMIC_ACQ_REL, __HIP_MEMORY_SCOPE_AGENT);
      while (__hip_atomic_load(&myctr[s], __ATOMIC_ACQUIRE, __HIP_MEMORY_SCOPE_AGENT) < 64) {
        __builtin_amdgcn_s_sleep(2);
      }
    }
    __syncthreads();
    __threadfence();
  }
}

// ---------------- emission features ----------------
__global__ void feats_kernel(const float* __restrict__ h1, const float* __restrict__ wout,
                             const float* __restrict__ bout, float* __restrict__ feats) {
  int bs = blockIdx.x;
  int lane = threadIdx.x;
  const float* hp = h1 + (size_t)bs * 512;
  float hv[8];
  #pragma unroll
  for (int i = 0; i < 8; i++) hv[i] = hp[lane + i * 64];
  #pragma unroll
  for (int t = 0; t < TT; t++) {
    const float* wp = wout + t * 512;
    float p = 0.f;
    #pragma unroll
    for (int i = 0; i < 8; i++) p += hv[i] * wp[lane + i * 64];
    #pragma unroll
    for (int off = 32; off >= 1; off >>= 1) p += __shfl_down(p, off, 64);
    if (lane == 0) feats[(size_t)bs * TT + t] = p + bout[t];
  }
}

// ---------------- Viterbi decode ----------------
__global__ void viterbi_kernel(const float* __restrict__ feats, const float* __restrict__ trans,
                               float* __restrict__ out) {
  int b = blockIdx.x;
  int lane = threadIdx.x;
  __shared__ float tr[121];
  __shared__ float fch[32 * TT];
  __shared__ unsigned char bp[SS][12];
  __shared__ unsigned char path[SS];
  for (int i = lane; i < 121; i += 64) tr[i] = trans[i];
  __syncthreads();
  int ln = lane < TT ? lane : (TT - 1);
  float trr[TT];
  #pragma unroll
  for (int p = 0; p < TT; p++) trr[p] = tr[ln * TT + p];
  float fv = (lane == 9) ? 0.f : NEGV;   // START = 9
  const float* fb = feats + (size_t)b * SS * TT;

  for (int s = 0; s < SS; s++) {
    if ((s & 31) == 0) {
      __syncthreads();
      for (int i = lane; i < 32 * TT; i += 64) fch[i] = fb[s * TT + i];
      __syncthreads();
    }
    float best = -3.0e38f; int arg = 0;
    #pragma unroll
    for (int p = 0; p < TT; p++) {
      float v = __shfl(fv, p, 64) + trr[p];
      if (v > best) { best = v; arg = p; }   // strict > keeps FIRST max (numpy argmax)
    }
    if (lane < TT) bp[s][lane] = (unsigned char)arg;
    fv = best + fch[(s & 31) * TT + ln];
  }
  float term = fv + tr[10 * TT + ln];        // STOP = 10
  float best = -3.0e38f; int arg = 0;
  #pragma unroll
  for (int p = 0; p < TT; p++) {
    float v = __shfl(term, p, 64);
    if (v > best) { best = v; arg = p; }
  }
  __syncthreads();
  if (lane == 0) {
    out[b] = best;
    int tg = arg;
    path[SS - 1] = (unsigned char)tg;
    for (int s = SS - 1; s >= 1; s--) {
      tg = bp[s][tg];
      path[s - 1] = (unsigned char)tg;
    }
  }
  __syncthreads();
  for (int i = lane; i < SS; i += 64) out[32 + b * SS + i] = (float)path[i];
}

// ---------------- launcher ----------------
extern "C" void kernel_launch(void* const* d_in, const int* in_sizes, int n_in,
                              void* d_out, int out_size, void* d_ws, size_t ws_size,
                              hipStream_t stream) {
  const int*   x     = (const int*)d_in[0];
  const float* emb   = (const float*)d_in[2];
  const float* wih0f = (const float*)d_in[3];
  const float* whh0f = (const float*)d_in[4];
  const float* b0f   = (const float*)d_in[5];
  const float* wih0b = (const float*)d_in[6];
  const float* whh0b = (const float*)d_in[7];
  const float* b0b   = (const float*)d_in[8];
  const float* wih1f = (const float*)d_in[9];
  const float* whh1f = (const float*)d_in[10];
  const float* b1f   = (const float*)d_in[11];
  const float* wih1b = (const float*)d_in[12];
  const float* whh1b = (const float*)d_in[13];
  const float* b1b   = (const float*)d_in[14];
  const float* wout  = (const float*)d_in[15];
  const float* bout  = (const float*)d_in[16];
  const float* trans = (const float*)d_in[17];

  char* ws = (char*)d_ws;
  float* xe    = (float*)(ws + OFF_XE);
  float* xs    = (float*)(ws + OFF_XS);
  float* h0    = (float*)(ws + OFF_H0);
  float* h1    = (float*)(ws + OFF_H1);
  float* feats = (float*)(ws + OFF_FEATS);
  float* hbuf  = (float*)(ws + OFF_HBUF);
  int*   ctr   = (int*)(ws + OFF_CTR);
  float* outp  = (float*)d_out;

  emb_kernel<<<4096, 256, 0, stream>>>(x, (const float4*)emb, (float4*)xe);
  proj_kernel<256><<<dim3(128, 8, 2), 256, 0, stream>>>(xe, wih0f, wih0b, b0f, b0b, xs);
  hipMemsetAsync(hbuf, 0, 131072 + 4096, stream);   // zero h ping-pong + barrier counters
  scan_kernel<<<dim3(64, 2), 256, 0, stream>>>(xs, whh0f, whh0b, hbuf, ctr, h0);
  proj_kernel<512><<<dim3(128, 8, 2), 256, 0, stream>>>(h0, wih1f, wih1b, b1f, b1b, xs);
  hipMemsetAsync(hbuf, 0, 131072 + 4096, stream);
  scan_kernel<<<dim3(64, 2), 256, 0, stream>>>(xs, whh1f, whh1b, hbuf, ctr, h1);
  feats_kernel<<<BB * SS, 64, 0, stream>>>(h1, wout, bout, feats);
  viterbi_kernel<<<BB, 64, 0, stream>>>(feats, trans, outp);
}

// Round 2
// 16466.527 us; speedup vs baseline: 1.7972x; 1.7972x over previous
//
#include <hip/hip_runtime.h>
#include <math.h>

#define SS 512
#define BB 32
#define HH 256
#define G4 1024
#define TT 11
#define NEGV (-1000.0f)

// ---------------- workspace layout (bytes) ----------------
static const size_t OFF_XE    = 0;                          // 16,777,216  : xe [B*S][256]
static const size_t OFF_XS    = 16777216ull;                // 134,217,728 : xs [2][S][B][1024]
static const size_t OFF_H0    = OFF_XS + 134217728ull;      // 33,554,432  : h0 [B*S][512]
static const size_t OFF_H1    = OFF_H0 + 33554432ull;       // 33,554,432  : h1 [B*S][512]
static const size_t OFF_FEATS = OFF_H1 + 33554432ull;       // 720,896     : feats [B][S][11]
static const size_t OFF_HBUF  = OFF_FEATS + 720896ull;      // 131,072     : h ping-pong [2 dir][2][B*256]
static const size_t OFF_CTR   = OFF_HBUF + 131072ull;       // 4,096       : flags [2][64] (+pad)
// total ~209 MB

// ---------------- embedding gather ----------------
__global__ void emb_kernel(const int* __restrict__ x, const float4* __restrict__ emb,
                           float4* __restrict__ xe) {
  int idx = blockIdx.x * 256 + threadIdx.x;    // over B*S*H/4 = 1,048,576
  int bs  = idx >> 6;
  int kq  = idx & 63;
  int row = x[bs];
  xe[idx] = emb[(size_t)row * 64 + kq];
}

// ---------------- input projection GEMM ----------------
// C[m][n] = sum_k A[m][k]*W[n][k] + bias[n]  -> xs[dir][s][b][n], m = b*S+s
// 128x128 tile, 256 threads, 8x8 micro-tile, BK=8
template<int K>
__global__ __launch_bounds__(256, 2)
void proj_kernel(const float* __restrict__ A,
                 const float* __restrict__ Wf, const float* __restrict__ Wb,
                 const float* __restrict__ bf, const float* __restrict__ bb,
                 float* __restrict__ xs) {
  __shared__ float As[8][132];
  __shared__ float Bs[8][132];
  int tid = threadIdx.x;
  int dir = blockIdx.z;
  const float* W    = dir ? Wb : Wf;
  const float* bias = dir ? bb : bf;
  float* out = xs + (size_t)dir * (SS * BB * G4);
  int bm = blockIdx.x * 128;
  int bn = blockIdx.y * 128;
  int ty = tid >> 4;
  int tx = tid & 15;
  int lr = tid >> 1;
  int lk = (tid & 1) * 4;
  const float* Ap = A + (size_t)(bm + lr) * K + lk;
  const float* Wp = W + (size_t)(bn + lr) * K + lk;
  float acc[8][8];
  #pragma unroll
  for (int i = 0; i < 8; i++)
    #pragma unroll
    for (int j = 0; j < 8; j++) acc[i][j] = 0.f;

  for (int kt = 0; kt < K; kt += 8) {
    float4 av = *(const float4*)(Ap + kt);
    float4 bv = *(const float4*)(Wp + kt);
    __syncthreads();
    As[lk + 0][lr] = av.x; As[lk + 1][lr] = av.y; As[lk + 2][lr] = av.z; As[lk + 3][lr] = av.w;
    Bs[lk + 0][lr] = bv.x; Bs[lk + 1][lr] = bv.y; Bs[lk + 2][lr] = bv.z; Bs[lk + 3][lr] = bv.w;
    __syncthreads();
    #pragma unroll
    for (int k = 0; k < 8; k++) {
      float4 a0 = *(const float4*)&As[k][ty * 8];
      float4 a1 = *(const float4*)&As[k][ty * 8 + 4];
      float4 b0 = *(const float4*)&Bs[k][tx * 8];
      float4 b1 = *(const float4*)&Bs[k][tx * 8 + 4];
      float a[8] = {a0.x, a0.y, a0.z, a0.w, a1.x, a1.y, a1.z, a1.w};
      float b[8] = {b0.x, b0.y, b0.z, b0.w, b1.x, b1.y, b1.z, b1.w};
      #pragma unroll
      for (int i = 0; i < 8; i++)
        #pragma unroll
        for (int j = 0; j < 8; j++)
          acc[i][j] += a[i] * b[j];
    }
  }
  int nb = bn + tx * 8;
  float4 bias0 = *(const float4*)(bias + nb);
  float4 bias1 = *(const float4*)(bias + nb + 4);
  #pragma unroll
  for (int i = 0; i < 8; i++) {
    int gm = bm + ty * 8 + i;
    int b_ = gm >> 9;
    int s_ = gm & 511;
    float* op = out + (size_t)(s_ * BB + b_) * G4 + nb;
    float4 v0, v1;
    v0.x = acc[i][0] + bias0.x; v0.y = acc[i][1] + bias0.y;
    v0.z = acc[i][2] + bias0.z; v0.w = acc[i][3] + bias0.w;
    v1.x = acc[i][4] + bias1.x; v1.y = acc[i][5] + bias1.y;
    v1.z = acc[i][6] + bias1.z; v1.w = acc[i][7] + bias1.w;
    *(float4*)op = v0;
    *(float4*)(op + 4) = v1;
  }
}

// ---------------- recurrent scan (one bidirectional LSTM layer) ----------------
// grid (64, 2): blockIdx.x = cell-group (4 cells), blockIdx.y = direction.
// Barrier: per-block flag (no contended RMW). Block cb release-stores
// flags[dir][cb]=s+1 after writing its h slice; wave 0 of every block polls all
// 64 flags with one 64-lane relaxed agent-scope atomic load. h itself moves via
// relaxed agent-scope atomic load/store (L2-bypassing, coherent) so NO acquire
// buffer_inv is ever issued -> xs stays warm in L2 for the whole kernel.
__global__ __launch_bounds__(256, 1)
void scan_kernel(const float* __restrict__ xs,      // [2][S][B][1024]
                 const float* __restrict__ whhf, const float* __restrict__ whhb,
                 float* __restrict__ hbuf,          // [2][2][B*256]
                 int* __restrict__ flg,             // [2][64]
                 float* __restrict__ hout)          // [B*S][512]
{
  int tid = threadIdx.x;
  int cb  = blockIdx.x;           // 0..63
  int dir = blockIdx.y;
  const float* whh = dir ? whhb : whhf;
  const float* xsd = xs + (size_t)dir * (SS * BB * G4);
  float* hb    = hbuf + (size_t)dir * (2 * BB * HH);
  int* myflg   = flg + dir * 64;

  __shared__ float h_sh[32 * 260];       // h[b][k] padded: row stride 260 floats (65 float4)
  __shared__ float part[4 * 16 * 33];    // partial[w][row_local][b]

  int w    = tid >> 6;           // wave index = k-slice
  int lane = tid & 63;
  int r8   = lane >> 3;          // row pair: rows r8*2, r8*2+1
  int b8   = lane & 7;           // batches b8 + 8*jb

  // preload weights into registers: wreg[i][j] = whh[grow(r8*2+i)][w*64 + j*4 ..+3]
  float4 wreg[2][16];
  #pragma unroll
  for (int i = 0; i < 2; i++) {
    int rl   = r8 * 2 + i;
    int grow = (rl >> 2) * 256 + cb * 4 + (rl & 3);
    const float* wp = whh + (size_t)grow * 256 + w * 64;
    #pragma unroll
    for (int j = 0; j < 16; j++) wreg[i][j] = *(const float4*)(wp + j * 4);
  }

  int uc = tid >> 5;    // cell 0..3 (valid for tid<128)
  int ub = tid & 31;    // batch
  float c_state = 0.f;

  for (int s = 0; s < SS; ++s) {
    int tpos = dir ? (SS - 1 - s) : s;

    // prefetch xs gate biases (normal loads, warm L2) BEFORE the poll
    float xsg[4] = {0.f, 0.f, 0.f, 0.f};
    if (tid < 128) {
      const float* xp = xsd + ((size_t)(tpos * BB + ub) * G4) + cb * 4 + uc;
      #pragma unroll
      for (int g = 0; g < 4; g++) xsg[g] = xp[g * 256];
    }

    // wait: all 64 blocks of this direction have published h for step s
    if (w == 0) {
      for (;;) {
        int f = __hip_atomic_load(&myflg[lane], __ATOMIC_RELAXED, __HIP_MEMORY_SCOPE_AGENT);
        if (__all(f >= s)) break;
      }
    }
    __syncthreads();   // releases waves 1-3; also compiler/mem barrier vs staging below

    // stage h(prev) into LDS via coherent (L2-bypassing) loads
    const float* hsrc = hb + (size_t)(s & 1) * (BB * HH);
    #pragma unroll
    for (int i = 0; i < 32; i++) {
      int idx = i * 256 + tid;           // b = i, k = tid
      h_sh[i * 260 + tid] =
          __hip_atomic_load(&hsrc[idx], __ATOMIC_RELAXED, __HIP_MEMORY_SCOPE_AGENT);
    }
    __syncthreads();

    // partial dot products over this wave's k-slice
    float acc[2][4] = {{0.f,0.f,0.f,0.f},{0.f,0.f,0.f,0.f}};
    #pragma unroll
    for (int j = 0; j < 16; j++) {
      int k4 = w * 16 + j;
      float4 h0 = *(const float4*)&h_sh[(b8 +  0) * 260 + k4 * 4];
      float4 h1 = *(const float4*)&h_sh[(b8 +  8) * 260 + k4 * 4];
      float4 h2 = *(const float4*)&h_sh[(b8 + 16) * 260 + k4 * 4];
      float4 h3 = *(const float4*)&h_sh[(b8 + 24) * 260 + k4 * 4];
      #pragma unroll
      for (int i = 0; i < 2; i++) {
        float4 wv = wreg[i][j];
        acc[i][0] += wv.x * h0.x + wv.y * h0.y + wv.z * h0.z + wv.w * h0.w;
        acc[i][1] += wv.x * h1.x + wv.y * h1.y + wv.z * h1.z + wv.w * h1.w;
        acc[i][2] += wv.x * h2.x + wv.y * h2.y + wv.z * h2.z + wv.w * h2.w;
        acc[i][3] += wv.x * h3.x + wv.y * h3.y + wv.z * h3.z + wv.w * h3.w;
      }
    }
    #pragma unroll
    for (int i = 0; i < 2; i++) {
      int rl = r8 * 2 + i;
      #pragma unroll
      for (int jb = 0; jb < 4; jb++)
        part[(w * 16 + rl) * 33 + (b8 + 8 * jb)] = acc[i][jb];
    }
    __syncthreads();

    // reduce + LSTM cell update (threads 0..127: 4 cells x 32 batches)
    if (tid < 128) {
      float gv[4];
      #pragma unroll
      for (int g = 0; g < 4; g++) {
        int rl = g * 4 + uc;
        float sum = xsg[g];
        #pragma unroll
        for (int ww = 0; ww < 4; ww++) sum += part[(ww * 16 + rl) * 33 + ub];
        gv[g] = sum;
      }
      float ig = 1.f / (1.f + expf(-gv[0]));
      float fg = 1.f / (1.f + expf(-gv[1]));
      float gg = tanhf(gv[2]);
      float og = 1.f / (1.f + expf(-gv[3]));
      c_state = fg * c_state + ig * gg;
      float hv = og * tanhf(c_state);
      int col = cb * 4 + uc;
      // publish h via coherent (L2-bypassing) store
      __hip_atomic_store(&hb[(size_t)((s + 1) & 1) * (BB * HH) + ub * HH + col], hv,
                         __ATOMIC_RELAXED, __HIP_MEMORY_SCOPE_AGENT);
      hout[((size_t)(ub * SS + tpos)) * 512 + dir * 256 + col] = hv;   // normal store
    }

    // all h stores issued & drained (syncthreads waits vmcnt(0)), then publish flag
    __syncthreads();
    if (tid == 0)
      __hip_atomic_store(&myflg[cb], s + 1, __ATOMIC_RELEASE, __HIP_MEMORY_SCOPE_AGENT);
  }
}

// ---------------- emission features ----------------
__global__ void feats_kernel(const float* __restrict__ h1, const float* __restrict__ wout,
                             const float* __restrict__ bout, float* __restrict__ feats) {
  int bs = blockIdx.x;
  int lane = threadIdx.x;
  const float* hp = h1 + (size_t)bs * 512;
  float hv[8];
  #pragma unroll
  for (int i = 0; i < 8; i++) hv[i] = hp[lane + i * 64];
  #pragma unroll
  for (int t = 0; t < TT; t++) {
    const float* wp = wout + t * 512;
    float p = 0.f;
    #pragma unroll
    for (int i = 0; i < 8; i++) p += hv[i] * wp[lane + i * 64];
    #pragma unroll
    for (int off = 32; off >= 1; off >>= 1) p += __shfl_down(p, off, 64);
    if (lane == 0) feats[(size_t)bs * TT + t] = p + bout[t];
  }
}

// ---------------- Viterbi decode ----------------
__global__ void viterbi_kernel(const float* __restrict__ feats, const float* __restrict__ trans,
                               float* __restrict__ out) {
  int b = blockIdx.x;
  int lane = threadIdx.x;
  __shared__ float tr[121];
  __shared__ float fch[32 * TT];
  __shared__ unsigned char bp[SS][12];
  __shared__ unsigned char path[SS];
  for (int i = lane; i < 121; i += 64) tr[i] = trans[i];
  __syncthreads();
  int ln = lane < TT ? lane : (TT - 1);
  float trr[TT];
  #pragma unroll
  for (int p = 0; p < TT; p++) trr[p] = tr[ln * TT + p];
  float fv = (lane == 9) ? 0.f : NEGV;   // START = 9
  const float* fb = feats + (size_t)b * SS * TT;

  for (int s = 0; s < SS; s++) {
    if ((s & 31) == 0) {
      __syncthreads();
      for (int i = lane; i < 32 * TT; i += 64) fch[i] = fb[s * TT + i];
      __syncthreads();
    }
    float best = -3.0e38f; int arg = 0;
    #pragma unroll
    for (int p = 0; p < TT; p++) {
      float v = __shfl(fv, p, 64) + trr[p];
      if (v > best) { best = v; arg = p; }   // strict > keeps FIRST max (numpy argmax)
    }
    if (lane < TT) bp[s][lane] = (unsigned char)arg;
    fv = best + fch[(s & 31) * TT + ln];
  }
  float term = fv + tr[10 * TT + ln];        // STOP = 10
  float best = -3.0e38f; int arg = 0;
  #pragma unroll
  for (int p = 0; p < TT; p++) {
    float v = __shfl(term, p, 64);
    if (v > best) { best = v; arg = p; }
  }
  __syncthreads();
  if (lane == 0) {
    out[b] = best;
    int tg = arg;
    path[SS - 1] = (unsigned char)tg;
    for (int s = SS - 1; s >= 1; s--) {
      tg = bp[s][tg];
      path[s - 1] = (unsigned char)tg;
    }
  }
  __syncthreads();
  for (int i = lane; i < SS; i += 64) out[32 + b * SS + i] = (float)path[i];
}

// ---------------- launcher ----------------
extern "C" void kernel_launch(void* const* d_in, const int* in_sizes, int n_in,
                              void* d_out, int out_size, void* d_ws, size_t ws_size,
                              hipStream_t stream) {
  const int*   x     = (const int*)d_in[0];
  const float* emb   = (const float*)d_in[2];
  const float* wih0f = (const float*)d_in[3];
  const float* whh0f = (const float*)d_in[4];
  const float* b0f   = (const float*)d_in[5];
  const float* wih0b = (const float*)d_in[6];
  const float* whh0b = (const float*)d_in[7];
  const float* b0b   = (const float*)d_in[8];
  const float* wih1f = (const float*)d_in[9];
  const float* whh1f = (const float*)d_in[10];
  const float* b1f   = (const float*)d_in[11];
  const float* wih1b = (const float*)d_in[12];
  const float* whh1b = (const float*)d_in[13];
  const float* b1b   = (const float*)d_in[14];
  const float* wout  = (const float*)d_in[15];
  const float* bout  = (const float*)d_in[16];
  const float* trans = (const float*)d_in[17];

  char* ws = (char*)d_ws;
  float* xe    = (float*)(ws + OFF_XE);
  float* xs    = (float*)(ws + OFF_XS);
  float* h0    = (float*)(ws + OFF_H0);
  float* h1    = (float*)(ws + OFF_H1);
  float* feats = (float*)(ws + OFF_FEATS);
  float* hbuf  = (float*)(ws + OFF_HBUF);
  int*   flg   = (int*)(ws + OFF_CTR);
  float* outp  = (float*)d_out;

  emb_kernel<<<4096, 256, 0, stream>>>(x, (const float4*)emb, (float4*)xe);
  proj_kernel<256><<<dim3(128, 8, 2), 256, 0, stream>>>(xe, wih0f, wih0b, b0f, b0b, xs);
  hipMemsetAsync(hbuf, 0, 131072 + 4096, stream);   // zero h ping-pong + flags
  scan_kernel<<<dim3(64, 2), 256, 0, stream>>>(xs, whh0f, whh0b, hbuf, flg, h0);
  proj_kernel<512><<<dim3(128, 8, 2), 256, 0, stream>>>(h0, wih1f, wih1b, b1f, b1b, xs);
  hipMemsetAsync(hbuf, 0, 131072 + 4096, stream);
  scan_kernel<<<dim3(64, 2), 256, 0, stream>>>(xs, whh1f, whh1b, hbuf, flg, h1);
  feats_kernel<<<BB * SS, 64, 0, stream>>>(h1, wout, bout, feats);
  viterbi_kernel<<<BB, 64, 0, stream>>>(feats, trans, outp);
}

// Round 3
// 6108.493 us; speedup vs baseline: 4.8448x; 2.6957x over previous
//
#include <hip/hip_runtime.h>
#include <math.h>

#define SS 512
#define BB 32
#define HH 256
#define G4 1024
#define TT 11
#define NEGV (-1000.0f)

// ---------------- workspace layout (bytes) ----------------
static const size_t OFF_XE    = 0;                          // 16,777,216  : xe [B*S][256]
static const size_t OFF_XS    = 16777216ull;                // 134,217,728 : xs [2][S][B][1024]
static const size_t OFF_H0    = OFF_XS + 134217728ull;      // 33,554,432  : h0 [B*S][512]
static const size_t OFF_H1    = OFF_H0 + 33554432ull;       // 33,554,432  : h1 [B*S][512]
static const size_t OFF_FEATS = OFF_H1 + 33554432ull;       // 720,896     : feats [B][S][11]
static const size_t OFF_HBUF  = OFF_FEATS + 720896ull;      // 131,072     : h ping-pong [2 dir][2][B*256]
static const size_t OFF_CTR   = OFF_HBUF + 131072ull;       // 4,096       : flags [2][64] (+pad)
// total ~209 MB

// ---------------- embedding gather ----------------
__global__ void emb_kernel(const int* __restrict__ x, const float4* __restrict__ emb,
                           float4* __restrict__ xe) {
  int idx = blockIdx.x * 256 + threadIdx.x;    // over B*S*H/4 = 1,048,576
  int bs  = idx >> 6;
  int kq  = idx & 63;
  int row = x[bs];
  xe[idx] = emb[(size_t)row * 64 + kq];
}

// ---------------- input projection GEMM ----------------
// C[m][n] = sum_k A[m][k]*W[n][k] + bias[n]  -> xs[dir][s][b][n], m = b*S+s
// 128x128 tile, 256 threads, 8x8 micro-tile, BK=8
template<int K>
__global__ __launch_bounds__(256, 2)
void proj_kernel(const float* __restrict__ A,
                 const float* __restrict__ Wf, const float* __restrict__ Wb,
                 const float* __restrict__ bf, const float* __restrict__ bb,
                 float* __restrict__ xs) {
  __shared__ float As[8][132];
  __shared__ float Bs[8][132];
  int tid = threadIdx.x;
  int dir = blockIdx.z;
  const float* W    = dir ? Wb : Wf;
  const float* bias = dir ? bb : bf;
  float* out = xs + (size_t)dir * (SS * BB * G4);
  int bm = blockIdx.x * 128;
  int bn = blockIdx.y * 128;
  int ty = tid >> 4;
  int tx = tid & 15;
  int lr = tid >> 1;
  int lk = (tid & 1) * 4;
  const float* Ap = A + (size_t)(bm + lr) * K + lk;
  const float* Wp = W + (size_t)(bn + lr) * K + lk;
  float acc[8][8];
  #pragma unroll
  for (int i = 0; i < 8; i++)
    #pragma unroll
    for (int j = 0; j < 8; j++) acc[i][j] = 0.f;

  for (int kt = 0; kt < K; kt += 8) {
    float4 av = *(const float4*)(Ap + kt);
    float4 bv = *(const float4*)(Wp + kt);
    __syncthreads();
    As[lk + 0][lr] = av.x; As[lk + 1][lr] = av.y; As[lk + 2][lr] = av.z; As[lk + 3][lr] = av.w;
    Bs[lk + 0][lr] = bv.x; Bs[lk + 1][lr] = bv.y; Bs[lk + 2][lr] = bv.z; Bs[lk + 3][lr] = bv.w;
    __syncthreads();
    #pragma unroll
    for (int k = 0; k < 8; k++) {
      float4 a0 = *(const float4*)&As[k][ty * 8];
      float4 a1 = *(const float4*)&As[k][ty * 8 + 4];
      float4 b0 = *(const float4*)&Bs[k][tx * 8];
      float4 b1 = *(const float4*)&Bs[k][tx * 8 + 4];
      float a[8] = {a0.x, a0.y, a0.z, a0.w, a1.x, a1.y, a1.z, a1.w};
      float b[8] = {b0.x, b0.y, b0.z, b0.w, b1.x, b1.y, b1.z, b1.w};
      #pragma unroll
      for (int i = 0; i < 8; i++)
        #pragma unroll
        for (int j = 0; j < 8; j++)
          acc[i][j] += a[i] * b[j];
    }
  }
  int nb = bn + tx * 8;
  float4 bias0 = *(const float4*)(bias + nb);
  float4 bias1 = *(const float4*)(bias + nb + 4);
  #pragma unroll
  for (int i = 0; i < 8; i++) {
    int gm = bm + ty * 8 + i;
    int b_ = gm >> 9;
    int s_ = gm & 511;
    float* op = out + (size_t)(s_ * BB + b_) * G4 + nb;
    float4 v0, v1;
    v0.x = acc[i][0] + bias0.x; v0.y = acc[i][1] + bias0.y;
    v0.z = acc[i][2] + bias0.z; v0.w = acc[i][3] + bias0.w;
    v1.x = acc[i][4] + bias1.x; v1.y = acc[i][5] + bias1.y;
    v1.z = acc[i][6] + bias1.z; v1.w = acc[i][7] + bias1.w;
    *(float4*)op = v0;
    *(float4*)(op + 4) = v1;
  }
}

// ---------------- recurrent scan (one bidirectional LSTM layer) ----------------
// grid (64, 2): blockIdx.x = cell-group (4 cells), blockIdx.y = direction.
// Cross-block protocol (no fences, no wbl2, no RMW):
//   - h moves via relaxed AGENT-scope atomics (sc0/sc1 -> L2-bypassing,
//     coherent at the common point). Readers never invalidate L2 -> xs stays
//     cached the whole kernel.
//   - ordering h-stores -> flag-store relies ONLY on __syncthreads(): each
//     wave's pre-barrier s_waitcnt vmcnt(0) drains its write-through h stores,
//     so after the barrier ALL h is globally visible; the flag store is then a
//     plain RELAXED atomic (NO release -> no per-step buffer_wbl2 flush).
//   - ping-pong buffers: block A may overwrite buffer (s&1) at step s+1 only
//     after seeing flag>=s+1 from every block, which is published only after
//     that block's reads of buffer (s&1) completed. Race-free.
__global__ __launch_bounds__(256, 1)
void scan_kernel(const float* __restrict__ xs,      // [2][S][B][1024]
                 const float* __restrict__ whhf, const float* __restrict__ whhb,
                 float* __restrict__ hbuf,          // [2][2][B*256]
                 int* __restrict__ flg,             // [2][64]
                 float* __restrict__ hout)          // [B*S][512]
{
  int tid = threadIdx.x;
  int cb  = blockIdx.x;           // 0..63
  int dir = blockIdx.y;
  const float* whh = dir ? whhb : whhf;
  const float* xsd = xs + (size_t)dir * (SS * BB * G4);
  float* hb    = hbuf + (size_t)dir * (2 * BB * HH);
  int* myflg   = flg + dir * 64;

  __shared__ float h_sh[32 * 260];       // h[b][k] padded: row stride 260 floats
  __shared__ float part[4 * 16 * 33];    // partial[w][row_local][b]

  int w    = tid >> 6;           // wave index = k-slice owner
  int lane = tid & 63;
  int r8   = lane >> 3;          // row pair: rows r8*2, r8*2+1
  int b8   = lane & 7;           // batches b8 + 8*jb
  int l5   = lane >> 5;          // 0/1 (staging)
  int j2   = lane & 31;          // float2 col within slice (staging)

  // preload weights into registers: wreg[i][j] = whh[grow(r8*2+i)][w*64 + j*4 ..+3]
  float4 wreg[2][16];
  #pragma unroll
  for (int i = 0; i < 2; i++) {
    int rl   = r8 * 2 + i;
    int grow = (rl >> 2) * 256 + cb * 4 + (rl & 3);
    const float* wp = whh + (size_t)grow * 256 + w * 64;
    #pragma unroll
    for (int j = 0; j < 16; j++) wreg[i][j] = *(const float4*)(wp + j * 4);
  }

  int uc = tid >> 5;    // cell 0..3 (valid for tid<128)
  int ub = tid & 31;    // batch
  float c_state = 0.f;
  float2* h_sh2 = (float2*)h_sh;

  for (int s = 0; s < SS; ++s) {
    int tpos = dir ? (SS - 1 - s) : s;

    // prefetch xs gate biases (normal loads, warm L2/L3) BEFORE the poll
    float xsg[4] = {0.f, 0.f, 0.f, 0.f};
    if (tid < 128) {
      const float* xp = xsd + ((size_t)(tpos * BB + ub) * G4) + cb * 4 + uc;
      #pragma unroll
      for (int g = 0; g < 4; g++) xsg[g] = xp[g * 256];
    }

    // wait: all 64 blocks of this direction have published h for step s
    if (w == 0) {
      for (;;) {
        int f = __hip_atomic_load(&myflg[lane], __ATOMIC_RELAXED, __HIP_MEMORY_SCOPE_AGENT);
        if (__all(f >= s)) break;
      }
    }
    __syncthreads();   // all waves: h(prev) is globally visible now

    // stage THIS WAVE'S k-slice of h(prev) into LDS via coherent 8B loads.
    // wave w consumes only k in [w*64, w*64+64) -> no cross-wave barrier needed.
    {
      const unsigned long long* hsrc8 =
          (const unsigned long long*)(hb + (size_t)(s & 1) * (BB * HH));
      unsigned long long hv8[16];
      #pragma unroll
      for (int i = 0; i < 16; i++) {
        int b_ = i * 2 + l5;
        hv8[i] = __hip_atomic_load(&hsrc8[b_ * 128 + w * 32 + j2],
                                   __ATOMIC_RELAXED, __HIP_MEMORY_SCOPE_AGENT);
      }
      #pragma unroll
      for (int i = 0; i < 16; i++) {
        int b_ = i * 2 + l5;
        float2 t; __builtin_memcpy(&t, &hv8[i], 8);
        h_sh2[b_ * 130 + w * 32 + j2] = t;
      }
    }

    // partial dot products over this wave's k-slice
    float acc[2][4] = {{0.f,0.f,0.f,0.f},{0.f,0.f,0.f,0.f}};
    #pragma unroll
    for (int j = 0; j < 16; j++) {
      int k4 = w * 16 + j;
      float4 h0 = *(const float4*)&h_sh[(b8 +  0) * 260 + k4 * 4];
      float4 h1 = *(const float4*)&h_sh[(b8 +  8) * 260 + k4 * 4];
      float4 h2 = *(const float4*)&h_sh[(b8 + 16) * 260 + k4 * 4];
      float4 h3 = *(const float4*)&h_sh[(b8 + 24) * 260 + k4 * 4];
      #pragma unroll
      for (int i = 0; i < 2; i++) {
        float4 wv = wreg[i][j];
        acc[i][0] += wv.x * h0.x + wv.y * h0.y + wv.z * h0.z + wv.w * h0.w;
        acc[i][1] += wv.x * h1.x + wv.y * h1.y + wv.z * h1.z + wv.w * h1.w;
        acc[i][2] += wv.x * h2.x + wv.y * h2.y + wv.z * h2.z + wv.w * h2.w;
        acc[i][3] += wv.x * h3.x + wv.y * h3.y + wv.z * h3.z + wv.w * h3.w;
      }
    }
    #pragma unroll
    for (int i = 0; i < 2; i++) {
      int rl = r8 * 2 + i;
      #pragma unroll
      for (int jb = 0; jb < 4; jb++)
        part[(w * 16 + rl) * 33 + (b8 + 8 * jb)] = acc[i][jb];
    }
    __syncthreads();

    // reduce + LSTM cell update (threads 0..127: 4 cells x 32 batches)
    if (tid < 128) {
      float gv[4];
      #pragma unroll
      for (int g = 0; g < 4; g++) {
        int rl = g * 4 + uc;
        float sum = xsg[g];
        #pragma unroll
        for (int ww = 0; ww < 4; ww++) sum += part[(ww * 16 + rl) * 33 + ub];
        gv[g] = sum;
      }
      float ig = 1.f / (1.f + expf(-gv[0]));
      float fg = 1.f / (1.f + expf(-gv[1]));
      float gg = tanhf(gv[2]);
      float og = 1.f / (1.f + expf(-gv[3]));
      c_state = fg * c_state + ig * gg;
      float hv = og * tanhf(c_state);
      int col = cb * 4 + uc;
      // publish h via coherent (L2-bypassing, write-through) store
      __hip_atomic_store(&hb[(size_t)((s + 1) & 1) * (BB * HH) + ub * HH + col], hv,
                         __ATOMIC_RELAXED, __HIP_MEMORY_SCOPE_AGENT);
      hout[((size_t)(ub * SS + tpos)) * 512 + dir * 256 + col] = hv;   // normal store
    }

    // __syncthreads: every wave drains vmcnt(0) before s_barrier -> all h
    // stores are at the coherence point. Flag can then be RELAXED (no wbl2).
    __syncthreads();
    if (tid == 0)
      __hip_atomic_store(&myflg[cb], s + 1, __ATOMIC_RELAXED, __HIP_MEMORY_SCOPE_AGENT);
  }
}

// ---------------- emission features ----------------
__global__ void feats_kernel(const float* __restrict__ h1, const float* __restrict__ wout,
                             const float* __restrict__ bout, float* __restrict__ feats) {
  int bs = blockIdx.x;
  int lane = threadIdx.x;
  const float* hp = h1 + (size_t)bs * 512;
  float hv[8];
  #pragma unroll
  for (int i = 0; i < 8; i++) hv[i] = hp[lane + i * 64];
  #pragma unroll
  for (int t = 0; t < TT; t++) {
    const float* wp = wout + t * 512;
    float p = 0.f;
    #pragma unroll
    for (int i = 0; i < 8; i++) p += hv[i] * wp[lane + i * 64];
    #pragma unroll
    for (int off = 32; off >= 1; off >>= 1) p += __shfl_down(p, off, 64);
    if (lane == 0) feats[(size_t)bs * TT + t] = p + bout[t];
  }
}

// ---------------- Viterbi decode ----------------
__global__ void viterbi_kernel(const float* __restrict__ feats, const float* __restrict__ trans,
                               float* __restrict__ out) {
  int b = blockIdx.x;
  int lane = threadIdx.x;
  __shared__ float tr[121];
  __shared__ float fch[32 * TT];
  __shared__ unsigned char bp[SS][12];
  __shared__ unsigned char path[SS];
  for (int i = lane; i < 121; i += 64) tr[i] = trans[i];
  __syncthreads();
  int ln = lane < TT ? lane : (TT - 1);
  float trr[TT];
  #pragma unroll
  for (int p = 0; p < TT; p++) trr[p] = tr[ln * TT + p];
  float fv = (lane == 9) ? 0.f : NEGV;   // START = 9
  const float* fb = feats + (size_t)b * SS * TT;

  for (int s = 0; s < SS; s++) {
    if ((s & 31) == 0) {
      __syncthreads();
      for (int i = lane; i < 32 * TT; i += 64) fch[i] = fb[s * TT + i];
      __syncthreads();
    }
    float best = -3.0e38f; int arg = 0;
    #pragma unroll
    for (int p = 0; p < TT; p++) {
      float v = __shfl(fv, p, 64) + trr[p];
      if (v > best) { best = v; arg = p; }   // strict > keeps FIRST max (numpy argmax)
    }
    if (lane < TT) bp[s][lane] = (unsigned char)arg;
    fv = best + fch[(s & 31) * TT + ln];
  }
  float term = fv + tr[10 * TT + ln];        // STOP = 10
  float best = -3.0e38f; int arg = 0;
  #pragma unroll
  for (int p = 0; p < TT; p++) {
    float v = __shfl(term, p, 64);
    if (v > best) { best = v; arg = p; }
  }
  __syncthreads();
  if (lane == 0) {
    out[b] = best;
    int tg = arg;
    path[SS - 1] = (unsigned char)tg;
    for (int s = SS - 1; s >= 1; s--) {
      tg = bp[s][tg];
      path[s - 1] = (unsigned char)tg;
    }
  }
  __syncthreads();
  for (int i = lane; i < SS; i += 64) out[32 + b * SS + i] = (float)path[i];
}

// ---------------- launcher ----------------
extern "C" void kernel_launch(void* const* d_in, const int* in_sizes, int n_in,
                              void* d_out, int out_size, void* d_ws, size_t ws_size,
                              hipStream_t stream) {
  const int*   x     = (const int*)d_in[0];
  const float* emb   = (const float*)d_in[2];
  const float* wih0f = (const float*)d_in[3];
  const float* whh0f = (const float*)d_in[4];
  const float* b0f   = (const float*)d_in[5];
  const float* wih0b = (const float*)d_in[6];
  const float* whh0b = (const float*)d_in[7];
  const float* b0b   = (const float*)d_in[8];
  const float* wih1f = (const float*)d_in[9];
  const float* whh1f = (const float*)d_in[10];
  const float* b1f   = (const float*)d_in[11];
  const float* wih1b = (const float*)d_in[12];
  const float* whh1b = (const float*)d_in[13];
  const float* b1b   = (const float*)d_in[14];
  const float* wout  = (const float*)d_in[15];
  const float* bout  = (const float*)d_in[16];
  const float* trans = (const float*)d_in[17];

  char* ws = (char*)d_ws;
  float* xe    = (float*)(ws + OFF_XE);
  float* xs    = (float*)(ws + OFF_XS);
  float* h0    = (float*)(ws + OFF_H0);
  float* h1    = (float*)(ws + OFF_H1);
  float* feats = (float*)(ws + OFF_FEATS);
  float* hbuf  = (float*)(ws + OFF_HBUF);
  int*   flg   = (int*)(ws + OFF_CTR);
  float* outp  = (float*)d_out;

  emb_kernel<<<4096, 256, 0, stream>>>(x, (const float4*)emb, (float4*)xe);
  proj_kernel<256><<<dim3(128, 8, 2), 256, 0, stream>>>(xe, wih0f, wih0b, b0f, b0b, xs);
  hipMemsetAsync(hbuf, 0, 131072 + 4096, stream);   // zero h ping-pong + flags
  scan_kernel<<<dim3(64, 2), 256, 0, stream>>>(xs, whh0f, whh0b, hbuf, flg, h0);
  proj_kernel<512><<<dim3(128, 8, 2), 256, 0, stream>>>(h0, wih1f, wih1b, b1f, b1b, xs);
  hipMemsetAsync(hbuf, 0, 131072 + 4096, stream);
  scan_kernel<<<dim3(64, 2), 256, 0, stream>>>(xs, whh1f, whh1b, hbuf, flg, h1);
  feats_kernel<<<BB * SS, 64, 0, stream>>>(h1, wout, bout, feats);
  viterbi_kernel<<<BB, 64, 0, stream>>>(feats, trans, outp);
}